// Round 4
// baseline (1589.902 us; speedup 1.0000x reference)
//
#include <hip/hip_runtime.h>
#include <stdint.h>

// Problem constants
#define MROWS 32768      // B*S = 8*4096
#define KD    256        // 2*DIM
#define VOCABN 8192

typedef _Float16 half8  __attribute__((ext_vector_type(8)));
typedef _Float16 half4v __attribute__((ext_vector_type(4)));
typedef float  floatx4  __attribute__((ext_vector_type(4)));

#define LDKB 144   // padded LDS row: 64 f16 = 128 B data + 16 B pad

// scratch layout (byte offsets within d_ws; verified ws_size >= WS_NEED in R3)
#define A_OFF     0u          // f16 z  [32768][256]  = 16,777,216 B
#define B_OFF     16777216u   // f16 cb [8192][256]   =  4,194,304 B
#define CN_OFF    20971520u   // f32 0.5*||c||^2 [8192] = 32,768 B
#define PART_OFF  21004288u   // float4 top2 [32768][8] = 4,194,304 B
#define IDX_OFF   25198592u   // int idx [32768] = 131,072 B
#define WS_NEED   25329664u

// ---- top-2 (max sigma) with smaller-index tie-break ----
struct Top2 { float s1; int i1; float s2; int i2; };

__device__ __forceinline__ bool better(float sa, int ia, float sb, int ib) {
    return (sa > sb) || (sa == sb && ia < ib);
}
__device__ __forceinline__ Top2 merge2(const Top2& a, const Top2& b) {
    Top2 r;
    if (better(b.s1, b.i1, a.s1, a.i1)) {
        r.s1 = b.s1; r.i1 = b.i1;
        if (better(a.s1, a.i1, b.s2, b.i2)) { r.s2 = a.s1; r.i2 = a.i1; }
        else                                { r.s2 = b.s2; r.i2 = b.i2; }
    } else {
        r.s1 = a.s1; r.i1 = a.i1;
        if (better(b.s1, b.i1, a.s2, a.i2)) { r.s2 = b.s1; r.i2 = b.i1; }
        else                                { r.s2 = a.s2; r.i2 = a.i2; }
    }
    return r;
}

// ---- 1. z = concat(real,imag) as f16 [32768][256] ----
__global__ __launch_bounds__(256) void prep_z(const float* __restrict__ gr,
                                              const float* __restrict__ gi,
                                              _Float16* __restrict__ A) {
    int t = blockIdx.x * 256 + threadIdx.x;     // 4 elements/thread
    int base = t * 4;
    int m = base >> 8;
    int k = base & 255;
    float4 v;
    if (k < 128) v = *(const float4*)(gr + (size_t)m * 128 + k);
    else         v = *(const float4*)(gi + (size_t)m * 128 + (k - 128));
    half4v h;
    h[0] = (_Float16)v.x; h[1] = (_Float16)v.y;
    h[2] = (_Float16)v.z; h[3] = (_Float16)v.w;
    *(half4v*)(A + base) = h;
}

// ---- 2. codebook f16 [8192][256] + 0.5*||c||^2 fp32 ----
__global__ __launch_bounds__(64) void prep_c(const float* __restrict__ cb,
                                             _Float16* __restrict__ B,
                                             float* __restrict__ cnorm) {
    int v = blockIdx.x;
    int lane = threadIdx.x;                    // 0..63, 4 floats each
    float4 c = ((const float4*)(cb + (size_t)v * 256))[lane];
    half4v h;
    h[0] = (_Float16)c.x; h[1] = (_Float16)c.y;
    h[2] = (_Float16)c.z; h[3] = (_Float16)c.w;
    ((half4v*)(B + (size_t)v * 256))[lane] = h;
    float s = c.x * c.x + c.y * c.y + c.z * c.z + c.w * c.w;
    #pragma unroll
    for (int m = 32; m; m >>= 1) s += __shfl_xor(s, m);
    if (lane == 0) cnorm[v] = 0.5f * s;
}

// ---- 3. f16 GEMM + per-row top-2 argmax(sigma), persistent over 8 N-tiles ----
// grid: (8, 256), block 256 (4 waves, 2x2). sigma = dot(z,c) - 0.5*||c||^2
__global__ __launch_bounds__(256) void gemm_argmin(const _Float16* __restrict__ A,
                                                   const _Float16* __restrict__ B,
                                                   const float* __restrict__ cnorm,
                                                   float4* __restrict__ part) {
    __shared__ __align__(16) char   smem[2 * 128 * LDKB];  // As / Bs
    __shared__ __align__(16) float4 topbuf[256];           // [128 rows][2 col-halves]
    __shared__ __align__(16) float4 rowtop[128];           // per-row running top2

    const int tid = threadIdx.x;
    const int bx = blockIdx.x, mb = blockIdx.y;
    const int m0 = mb * 128;
    const int wave = tid >> 6, lane = tid & 63;
    const int wr = wave >> 1, wc = wave & 1;
    const int lane16 = lane & 15, quad = lane >> 4;

    char* As = smem;
    char* Bs = smem + 128 * LDKB;

    if (tid < 128)
        rowtop[tid] = make_float4(-3.4e38f, __int_as_float(0x7fffffff),
                                  -3.4e38f, __int_as_float(0x7fffffff));
    __syncthreads();

    for (int g = 0; g < 8; ++g) {
        const int n0 = (bx * 8 + g) * 128;

        float hc[4];
        #pragma unroll
        for (int j = 0; j < 4; ++j)
            hc[j] = cnorm[n0 + wc * 64 + j * 16 + lane16];

        floatx4 acc[4][4];
        #pragma unroll
        for (int i = 0; i < 4; ++i)
            #pragma unroll
            for (int j = 0; j < 4; ++j)
                acc[i][j] = (floatx4){0.f, 0.f, 0.f, 0.f};

        for (int s = 0; s < 4; ++s) {
            const int k0 = s * 64;
            // each tile: 128 rows x 64 f16 = 1024 16B chunks; 4 per thread per matrix
            uint4 av[4], bv[4];
            #pragma unroll
            for (int it = 0; it < 4; ++it) {
                int c = it * 256 + tid;        // 0..1023
                int r = c >> 3, ci = c & 7;
                av[it] = *(const uint4*)(A + (size_t)(m0 + r) * 256 + k0 + ci * 8);
                bv[it] = *(const uint4*)(B + (size_t)(n0 + r) * 256 + k0 + ci * 8);
            }
            __syncthreads();   // previous stage's LDS reads complete
            #pragma unroll
            for (int it = 0; it < 4; ++it) {
                int c = it * 256 + tid;
                int r = c >> 3, ci = c & 7;
                *(uint4*)(As + r * LDKB + ci * 16) = av[it];
                *(uint4*)(Bs + r * LDKB + ci * 16) = bv[it];
            }
            __syncthreads();
            #pragma unroll
            for (int ks = 0; ks < 2; ++ks) {
                half8 af[4], bf[4];
                #pragma unroll
                for (int i = 0; i < 4; ++i) {
                    af[i] = *(const half8*)(As +
                            (wr * 64 + i * 16 + lane16) * LDKB + ks * 64 + quad * 16);
                    bf[i] = *(const half8*)(Bs +
                            (wc * 64 + i * 16 + lane16) * LDKB + ks * 64 + quad * 16);
                }
                #pragma unroll
                for (int i = 0; i < 4; ++i)
                    #pragma unroll
                    for (int j = 0; j < 4; ++j)
                        acc[i][j] = __builtin_amdgcn_mfma_f32_16x16x32_f16(
                            af[i], bf[j], acc[i][j], 0, 0, 0);
            }
        }
        __syncthreads();

        // epilogue; C/D layout: col=lane&15, row=quad*4+reg [m89]
        #pragma unroll
        for (int i = 0; i < 4; ++i) {
            #pragma unroll
            for (int r = 0; r < 4; ++r) {
                Top2 t; t.s1 = -3.4e38f; t.i1 = 0x7fffffff;
                        t.s2 = -3.4e38f; t.i2 = 0x7fffffff;
                #pragma unroll
                for (int j = 0; j < 4; ++j) {
                    float sv = acc[i][j][r] - hc[j];
                    int col = n0 + wc * 64 + j * 16 + lane16;
                    if (better(sv, col, t.s1, t.i1)) {
                        t.s2 = t.s1; t.i2 = t.i1; t.s1 = sv; t.i1 = col;
                    } else if (better(sv, col, t.s2, t.i2)) {
                        t.s2 = sv; t.i2 = col;
                    }
                }
                #pragma unroll
                for (int m = 1; m < 16; m <<= 1) {
                    Top2 o;
                    o.s1 = __shfl_xor(t.s1, m); o.i1 = __shfl_xor(t.i1, m);
                    o.s2 = __shfl_xor(t.s2, m); o.i2 = __shfl_xor(t.i2, m);
                    t = merge2(t, o);
                }
                if (lane16 == 0) {
                    int rl = wr * 64 + i * 16 + quad * 4 + r;
                    topbuf[rl * 2 + wc] =
                        make_float4(t.s1, __int_as_float(t.i1),
                                    t.s2, __int_as_float(t.i2));
                }
            }
        }
        __syncthreads();
        if (tid < 128) {
            float4 e0 = topbuf[tid * 2 + 0], e1 = topbuf[tid * 2 + 1], rv = rowtop[tid];
            Top2 a{e0.x, __float_as_int(e0.y), e0.z, __float_as_int(e0.w)};
            Top2 b{e1.x, __float_as_int(e1.y), e1.z, __float_as_int(e1.w)};
            Top2 p{rv.x, __float_as_int(rv.y), rv.z, __float_as_int(rv.w)};
            Top2 t = merge2(merge2(a, b), p);
            rowtop[tid] = make_float4(t.s1, __int_as_float(t.i1),
                                      t.s2, __int_as_float(t.i2));
        }
        __syncthreads();
    }

    if (tid < 128)
        part[(size_t)(m0 + tid) * 8 + bx] = rowtop[tid];
}

// ---- 4. resolve: merge 8 partials/row, fp64-refine near-ties, write idx ----
__global__ __launch_bounds__(256) void resolve(const float4* __restrict__ part,
                                               const float* __restrict__ gr,
                                               const float* __restrict__ gi,
                                               const float* __restrict__ cb,
                                               int* __restrict__ idx) {
    const int row = blockIdx.x * 256 + threadIdx.x;   // grid 128
    float4 e[8];
    #pragma unroll
    for (int j = 0; j < 8; ++j) e[j] = part[(size_t)row * 8 + j];
    Top2 t{-3.4e38f, 0x7fffffff, -3.4e38f, 0x7fffffff};
    #pragma unroll
    for (int j = 0; j < 8; ++j) {
        Top2 o{e[j].x, __float_as_int(e[j].y), e[j].z, __float_as_int(e[j].w)};
        t = merge2(t, o);
    }
    int best = t.i1;
    const float MARGIN = 0.12f;   // ~11 sigma of f16-screen noise (~0.011)
    if (t.s1 - t.s2 < MARGIN) {
        double bd = 1e300; int bi = 0x7fffffff;
        float cut = t.s1 - MARGIN;
        const float* zr = gr + (size_t)row * 128;
        const float* zi = gi + (size_t)row * 128;
        #pragma unroll
        for (int j = 0; j < 8; ++j) {
            #pragma unroll
            for (int c = 0; c < 2; ++c) {
                float sv = c ? e[j].z : e[j].x;
                int   ci = __float_as_int(c ? e[j].w : e[j].y);
                if (sv >= cut && (unsigned)ci < 8192u) {   // clamp: no wild reads
                    const float* crow = cb + (size_t)ci * 256;
                    double d = 0.0;
                    for (int k = 0; k < 128; ++k) {
                        double a = (double)zr[k] - (double)crow[k];
                        double b = (double)zi[k] - (double)crow[128 + k];
                        d += a * a + b * b;
                    }
                    if (d < bd || (d == bd && ci < bi)) { bd = d; bi = ci; }
                }
            }
        }
        if ((unsigned)bi < 8192u) best = bi;
    }
    idx[row] = ((unsigned)best < 8192u) ? best : 0;
}

// ---- 5a. zero the vq accumulator ----
__global__ void zero_vq(float* __restrict__ out, size_t vq_off) {
    out[vq_off] = 0.f;
}

// ---- 5b. gather + proposal(REAL part only) + salience + vq (one wave/row) ----
// Output layout (out_size = 4227073 floats):
//   [0, 4194304)          proposal = real(z_q) = codebook[idx][0:128], row-major
//   [4194304, 4227072)    salience [32768]
//   [4227072]             vq_loss
__global__ __launch_bounds__(256) void gather_epi(const int* __restrict__ idx,
                                                  const float* __restrict__ gr,
                                                  const float* __restrict__ gi,
                                                  const float* __restrict__ cb,
                                                  const float* __restrict__ salw,
                                                  const float* __restrict__ salb,
                                                  float* __restrict__ out,
                                                  size_t sal_off, size_t vq_off) {
    const int wave = threadIdx.x >> 6, lane = threadIdx.x & 63;
    const int row = blockIdx.x * 4 + wave;
    int id = idx[row];
    if ((unsigned)id >= 8192u) id = 0;   // clamp: no wild reads

    float4 c4 = ((const float4*)(cb + (size_t)id * 256))[lane];
    float4 z4 = (lane < 32) ? ((const float4*)(gr + (size_t)row * 128))[lane]
                            : ((const float4*)(gi + (size_t)row * 128))[lane - 32];

    float dx = c4.x - z4.x, dy = c4.y - z4.y, dz = c4.z - z4.z, dw = c4.w - z4.w;
    float vq = dx * dx + dy * dy + dz * dz + dw * dw;
    float4 w4 = ((const float4*)salw)[lane];
    float sal = c4.x * w4.x + c4.y * w4.y + c4.z * w4.z + c4.w * w4.w;
    #pragma unroll
    for (int m = 1; m < 64; m <<= 1) {
        vq  += __shfl_xor(vq, m);
        sal += __shfl_xor(sal, m);
    }

    // proposal: real part only — lanes 0..31 hold c[0..128) as float4s
    if (lane < 32 && (size_t)(row + 1) * 128 <= sal_off) {
        float4* op = (float4*)(out + (size_t)row * 128);
        op[lane] = c4;
    }
    if (lane == 0 && sal_off + row < vq_off)
        out[sal_off + row] = sal + salb[0];

    __shared__ float vqs[4];
    if (lane == 0) vqs[wave] = vq;
    __syncthreads();
    if (threadIdx.x == 0) {
        float p = (vqs[0] + vqs[1] + vqs[2] + vqs[3]) * (1.25f / 8388608.f);
        atomicAdd(out + vq_off, p);
    }
}

extern "C" void kernel_launch(void* const* d_in, const int* in_sizes, int n_in,
                              void* d_out, int out_size, void* d_ws, size_t ws_size,
                              hipStream_t stream) {
    const float* gr = (const float*)d_in[0];   // gw_real  [8,4096,128]
    const float* gi = (const float*)d_in[1];   // gw_imag  [8,4096,128]
    const float* cb = (const float*)d_in[2];   // codebook [8192,256]
    const float* sw = (const float*)d_in[3];   // sal_w    [1,256]
    const float* sb = (const float*)d_in[4];   // sal_b    [1]
    float* out = (float*)d_out;

    // Output offsets derived from runtime out_size (expected 4,227,073 floats:
    // proposal-real 4,194,304 | salience 32,768 | vq_loss 1).
    size_t vq_off  = (size_t)out_size - 1;
    size_t sal_off = (size_t)out_size - 1 - 32768;

    // R3 evidence: no fault with ws path active => ws_size >= WS_NEED.
    char* base = (char*)d_ws;
    int*  idxb = (int*)(base + IDX_OFF);
    _Float16* A    = (_Float16*)(base + A_OFF);
    _Float16* Bq   = (_Float16*)(base + B_OFF);
    float*    cn   = (float*)   (base + CN_OFF);
    float4*   part = (float4*)  (base + PART_OFF);

    prep_z<<<8192, 256, 0, stream>>>(gr, gi, A);
    prep_c<<<8192, 64, 0, stream>>>(cb, Bq, cn);
    gemm_argmin<<<dim3(8, 256), 256, 0, stream>>>(A, Bq, cn, part);
    resolve<<<128, 256, 0, stream>>>(part, gr, gi, cb, idxb);
    zero_vq<<<1, 1, 0, stream>>>(out, vq_off);
    gather_epi<<<8192, 256, 0, stream>>>(idxb, gr, gi, cb, sw, sb, out,
                                         sal_off, vq_off);
}

// Round 9
// 1588.737 us; speedup vs baseline: 1.0007x; 1.0007x over previous
//
#include <hip/hip_runtime.h>
#include <stdint.h>

// Problem constants
#define MROWS 32768      // B*S = 8*4096
#define KD    256        // 2*DIM
#define VOCABN 8192

typedef _Float16 half8  __attribute__((ext_vector_type(8)));
typedef _Float16 half4v __attribute__((ext_vector_type(4)));
typedef float  floatx4  __attribute__((ext_vector_type(4)));

#define LDKB 144   // padded LDS row: 64 f16 = 128 B data + 16 B pad

// scratch layout (byte offsets within d_ws; ws_size >= WS_NEED verified R3/R4)
#define A_OFF     0u          // f16 z  [32768][256]  = 16,777,216 B
#define B_OFF     16777216u   // f16 cb [8192][256]   =  4,194,304 B
#define CN_OFF    20971520u   // f32 0.5*||c||^2 [8192] = 32,768 B
#define PART_OFF  21004288u   // float4 top2 [32768][8] = 4,194,304 B
#define IDX_OFF   25198592u   // int idx [32768] = 131,072 B
#define WS_NEED   25329664u

// ---- top-2 (max sigma) with smaller-index tie-break ----
struct Top2 { float s1; int i1; float s2; int i2; };

__device__ __forceinline__ bool better(float sa, int ia, float sb, int ib) {
    return (sa > sb) || (sa == sb && ia < ib);
}
__device__ __forceinline__ Top2 merge2(const Top2& a, const Top2& b) {
    Top2 r;
    if (better(b.s1, b.i1, a.s1, a.i1)) {
        r.s1 = b.s1; r.i1 = b.i1;
        if (better(a.s1, a.i1, b.s2, b.i2)) { r.s2 = a.s1; r.i2 = a.i1; }
        else                                { r.s2 = b.s2; r.i2 = b.i2; }
    } else {
        r.s1 = a.s1; r.i1 = a.i1;
        if (better(b.s1, b.i1, a.s2, a.i2)) { r.s2 = b.s1; r.i2 = b.i1; }
        else                                { r.s2 = a.s2; r.i2 = a.i2; }
    }
    return r;
}

// ---- 1. z = concat(real,imag) as f16 [32768][256] ----
__global__ __launch_bounds__(256) void prep_z(const float* __restrict__ gr,
                                              const float* __restrict__ gi,
                                              _Float16* __restrict__ A) {
    int t = blockIdx.x * 256 + threadIdx.x;     // 4 elements/thread
    int base = t * 4;
    int m = base >> 8;
    int k = base & 255;
    float4 v;
    if (k < 128) v = *(const float4*)(gr + (size_t)m * 128 + k);
    else         v = *(const float4*)(gi + (size_t)m * 128 + (k - 128));
    half4v h;
    h[0] = (_Float16)v.x; h[1] = (_Float16)v.y;
    h[2] = (_Float16)v.z; h[3] = (_Float16)v.w;
    *(half4v*)(A + base) = h;
}

// ---- 2. codebook f16 [8192][256] + 0.5*||c||^2 fp32 ----
__global__ __launch_bounds__(64) void prep_c(const float* __restrict__ cb,
                                             _Float16* __restrict__ B,
                                             float* __restrict__ cnorm) {
    int v = blockIdx.x;
    int lane = threadIdx.x;                    // 0..63, 4 floats each
    float4 c = ((const float4*)(cb + (size_t)v * 256))[lane];
    half4v h;
    h[0] = (_Float16)c.x; h[1] = (_Float16)c.y;
    h[2] = (_Float16)c.z; h[3] = (_Float16)c.w;
    ((half4v*)(B + (size_t)v * 256))[lane] = h;
    float s = c.x * c.x + c.y * c.y + c.z * c.z + c.w * c.w;
    #pragma unroll
    for (int m = 32; m; m >>= 1) s += __shfl_xor(s, m);
    if (lane == 0) cnorm[v] = 0.5f * s;
}

// ---- 3. f16 GEMM + per-row top-2 argmax(sigma), persistent over 8 N-tiles ----
// VERBATIM R4-passing kernel except the grid-axis swap: M-tile is now
// blockIdx.x (fastest) and the N-super-group blockIdx.y (slowest), so all
// co-resident blocks share ONE 512 KB B-strip -> B served from L2 instead of
// thrashing (R4 counters: FETCH 721 MB, 1.26 TB/s, MfmaUtil 4%).
// grid: dim3(256, 8), block 256 (4 waves, 2x2). sigma = dot(z,c)-0.5*||c||^2
__global__ __launch_bounds__(256) void gemm_argmin(const _Float16* __restrict__ A,
                                                   const _Float16* __restrict__ B,
                                                   const float* __restrict__ cnorm,
                                                   float4* __restrict__ part) {
    __shared__ __align__(16) char   smem[2 * 128 * LDKB];  // As / Bs
    __shared__ __align__(16) float4 topbuf[256];           // [128 rows][2 col-halves]
    __shared__ __align__(16) float4 rowtop[128];           // per-row running top2

    const int tid = threadIdx.x;
    const int bx = blockIdx.y, mb = blockIdx.x;            // SWAPPED vs R4
    const int m0 = mb * 128;
    const int wave = tid >> 6, lane = tid & 63;
    const int wr = wave >> 1, wc = wave & 1;
    const int lane16 = lane & 15, quad = lane >> 4;

    char* As = smem;
    char* Bs = smem + 128 * LDKB;

    if (tid < 128)
        rowtop[tid] = make_float4(-3.4e38f, __int_as_float(0x7fffffff),
                                  -3.4e38f, __int_as_float(0x7fffffff));
    __syncthreads();

    for (int g = 0; g < 8; ++g) {
        const int n0 = (bx * 8 + g) * 128;

        float hc[4];
        #pragma unroll
        for (int j = 0; j < 4; ++j)
            hc[j] = cnorm[n0 + wc * 64 + j * 16 + lane16];

        floatx4 acc[4][4];
        #pragma unroll
        for (int i = 0; i < 4; ++i)
            #pragma unroll
            for (int j = 0; j < 4; ++j)
                acc[i][j] = (floatx4){0.f, 0.f, 0.f, 0.f};

        for (int s = 0; s < 4; ++s) {
            const int k0 = s * 64;
            // each tile: 128 rows x 64 f16 = 1024 16B chunks; 4 per thread per matrix
            uint4 av[4], bv[4];
            #pragma unroll
            for (int it = 0; it < 4; ++it) {
                int c = it * 256 + tid;        // 0..1023
                int r = c >> 3, ci = c & 7;
                av[it] = *(const uint4*)(A + (size_t)(m0 + r) * 256 + k0 + ci * 8);
                bv[it] = *(const uint4*)(B + (size_t)(n0 + r) * 256 + k0 + ci * 8);
            }
            __syncthreads();   // previous stage's LDS reads complete
            #pragma unroll
            for (int it = 0; it < 4; ++it) {
                int c = it * 256 + tid;
                int r = c >> 3, ci = c & 7;
                *(uint4*)(As + r * LDKB + ci * 16) = av[it];
                *(uint4*)(Bs + r * LDKB + ci * 16) = bv[it];
            }
            __syncthreads();
            #pragma unroll
            for (int ks = 0; ks < 2; ++ks) {
                half8 af[4], bf[4];
                #pragma unroll
                for (int i = 0; i < 4; ++i) {
                    af[i] = *(const half8*)(As +
                            (wr * 64 + i * 16 + lane16) * LDKB + ks * 64 + quad * 16);
                    bf[i] = *(const half8*)(Bs +
                            (wc * 64 + i * 16 + lane16) * LDKB + ks * 64 + quad * 16);
                }
                #pragma unroll
                for (int i = 0; i < 4; ++i)
                    #pragma unroll
                    for (int j = 0; j < 4; ++j)
                        acc[i][j] = __builtin_amdgcn_mfma_f32_16x16x32_f16(
                            af[i], bf[j], acc[i][j], 0, 0, 0);
            }
        }
        __syncthreads();

        // epilogue; C/D layout: col=lane&15, row=quad*4+reg [m89]
        #pragma unroll
        for (int i = 0; i < 4; ++i) {
            #pragma unroll
            for (int r = 0; r < 4; ++r) {
                Top2 t; t.s1 = -3.4e38f; t.i1 = 0x7fffffff;
                        t.s2 = -3.4e38f; t.i2 = 0x7fffffff;
                #pragma unroll
                for (int j = 0; j < 4; ++j) {
                    float sv = acc[i][j][r] - hc[j];
                    int col = n0 + wc * 64 + j * 16 + lane16;
                    if (better(sv, col, t.s1, t.i1)) {
                        t.s2 = t.s1; t.i2 = t.i1; t.s1 = sv; t.i1 = col;
                    } else if (better(sv, col, t.s2, t.i2)) {
                        t.s2 = sv; t.i2 = col;
                    }
                }
                #pragma unroll
                for (int m = 1; m < 16; m <<= 1) {
                    Top2 o;
                    o.s1 = __shfl_xor(t.s1, m); o.i1 = __shfl_xor(t.i1, m);
                    o.s2 = __shfl_xor(t.s2, m); o.i2 = __shfl_xor(t.i2, m);
                    t = merge2(t, o);
                }
                if (lane16 == 0) {
                    int rl = wr * 64 + i * 16 + quad * 4 + r;
                    topbuf[rl * 2 + wc] =
                        make_float4(t.s1, __int_as_float(t.i1),
                                    t.s2, __int_as_float(t.i2));
                }
            }
        }
        __syncthreads();
        if (tid < 128) {
            float4 e0 = topbuf[tid * 2 + 0], e1 = topbuf[tid * 2 + 1], rv = rowtop[tid];
            Top2 a{e0.x, __float_as_int(e0.y), e0.z, __float_as_int(e0.w)};
            Top2 b{e1.x, __float_as_int(e1.y), e1.z, __float_as_int(e1.w)};
            Top2 p{rv.x, __float_as_int(rv.y), rv.z, __float_as_int(rv.w)};
            Top2 t = merge2(merge2(a, b), p);
            rowtop[tid] = make_float4(t.s1, __int_as_float(t.i1),
                                      t.s2, __int_as_float(t.i2));
        }
        __syncthreads();
    }

    if (tid < 128)
        part[(size_t)(m0 + tid) * 8 + bx] = rowtop[tid];
}

// ---- 4. resolve: merge 8 partials/row, fp64-refine near-ties (R4-proven) ----
__global__ __launch_bounds__(256) void resolve(const float4* __restrict__ part,
                                               const float* __restrict__ gr,
                                               const float* __restrict__ gi,
                                               const float* __restrict__ cb,
                                               int* __restrict__ idx) {
    const int row = blockIdx.x * 256 + threadIdx.x;   // grid 128
    float4 e[8];
    #pragma unroll
    for (int j = 0; j < 8; ++j) e[j] = part[(size_t)row * 8 + j];
    Top2 t{-3.4e38f, 0x7fffffff, -3.4e38f, 0x7fffffff};
    #pragma unroll
    for (int j = 0; j < 8; ++j) {
        Top2 o{e[j].x, __float_as_int(e[j].y), e[j].z, __float_as_int(e[j].w)};
        t = merge2(t, o);
    }
    int best = t.i1;
    const float MARGIN = 0.12f;   // ~7.7 sigma of f16-screen score-diff noise
    if (t.s1 - t.s2 < MARGIN) {
        double bd = 1e300; int bi = 0x7fffffff;
        float cut = t.s1 - MARGIN;
        const float* zr = gr + (size_t)row * 128;
        const float* zi = gi + (size_t)row * 128;
        #pragma unroll
        for (int j = 0; j < 8; ++j) {
            #pragma unroll
            for (int c = 0; c < 2; ++c) {
                float sv = c ? e[j].z : e[j].x;
                int   ci = __float_as_int(c ? e[j].w : e[j].y);
                if (sv >= cut && (unsigned)ci < 8192u) {   // clamp: no wild reads
                    const float* crow = cb + (size_t)ci * 256;
                    double d = 0.0;
                    for (int k = 0; k < 128; ++k) {
                        double a = (double)zr[k] - (double)crow[k];
                        double b = (double)zi[k] - (double)crow[128 + k];
                        d += a * a + b * b;
                    }
                    if (d < bd || (d == bd && ci < bi)) { bd = d; bi = ci; }
                }
            }
        }
        if ((unsigned)bi < 8192u) best = bi;
    }
    idx[row] = ((unsigned)best < 8192u) ? best : 0;
}

// ---- 5a. zero the vq accumulator ----
__global__ void zero_vq(float* __restrict__ out, size_t vq_off) {
    out[vq_off] = 0.f;
}

// ---- 5b. gather + proposal(REAL part only) + salience + vq (one wave/row) ----
__global__ __launch_bounds__(256) void gather_epi(const int* __restrict__ idx,
                                                  const float* __restrict__ gr,
                                                  const float* __restrict__ gi,
                                                  const float* __restrict__ cb,
                                                  const float* __restrict__ salw,
                                                  const float* __restrict__ salb,
                                                  float* __restrict__ out,
                                                  size_t sal_off, size_t vq_off) {
    const int wave = threadIdx.x >> 6, lane = threadIdx.x & 63;
    const int row = blockIdx.x * 4 + wave;
    int id = idx[row];
    if ((unsigned)id >= 8192u) id = 0;   // clamp: no wild reads

    float4 c4 = ((const float4*)(cb + (size_t)id * 256))[lane];
    float4 z4 = (lane < 32) ? ((const float4*)(gr + (size_t)row * 128))[lane]
                            : ((const float4*)(gi + (size_t)row * 128))[lane - 32];

    float dx = c4.x - z4.x, dy = c4.y - z4.y, dz = c4.z - z4.z, dw = c4.w - z4.w;
    float vq = dx * dx + dy * dy + dz * dz + dw * dw;
    float4 w4 = ((const float4*)salw)[lane];
    float sal = c4.x * w4.x + c4.y * w4.y + c4.z * w4.z + c4.w * w4.w;
    #pragma unroll
    for (int m = 1; m < 64; m <<= 1) {
        vq  += __shfl_xor(vq, m);
        sal += __shfl_xor(sal, m);
    }

    // proposal: real part only — lanes 0..31 hold c[0..128) as float4s
    if (lane < 32 && (size_t)(row + 1) * 128 <= sal_off) {
        float4* op = (float4*)(out + (size_t)row * 128);
        op[lane] = c4;
    }
    if (lane == 0 && sal_off + row < vq_off)
        out[sal_off + row] = sal + salb[0];

    __shared__ float vqs[4];
    if (lane == 0) vqs[wave] = vq;
    __syncthreads();
    if (threadIdx.x == 0) {
        float p = (vqs[0] + vqs[1] + vqs[2] + vqs[3]) * (1.25f / 8388608.f);
        atomicAdd(out + vq_off, p);
    }
}

extern "C" void kernel_launch(void* const* d_in, const int* in_sizes, int n_in,
                              void* d_out, int out_size, void* d_ws, size_t ws_size,
                              hipStream_t stream) {
    const float* gr = (const float*)d_in[0];   // gw_real  [8,4096,128]
    const float* gi = (const float*)d_in[1];   // gw_imag  [8,4096,128]
    const float* cb = (const float*)d_in[2];   // codebook [8192,256]
    const float* sw = (const float*)d_in[3];   // sal_w    [1,256]
    const float* sb = (const float*)d_in[4];   // sal_b    [1]
    float* out = (float*)d_out;

    // Output offsets (out_size = 4,227,073 floats:
    // proposal-real 4,194,304 | salience 32,768 | vq_loss 1).
    size_t vq_off  = (size_t)out_size - 1;
    size_t sal_off = (size_t)out_size - 1 - 32768;

    char* base = (char*)d_ws;
    int*  idxb = (int*)(base + IDX_OFF);
    _Float16* A    = (_Float16*)(base + A_OFF);
    _Float16* Bq   = (_Float16*)(base + B_OFF);
    float*    cn   = (float*)   (base + CN_OFF);
    float4*   part = (float4*)  (base + PART_OFF);

    prep_z<<<8192, 256, 0, stream>>>(gr, gi, A);
    prep_c<<<8192, 64, 0, stream>>>(cb, Bq, cn);
    gemm_argmin<<<dim3(256, 8), 256, 0, stream>>>(A, Bq, cn, part);   // M fastest
    resolve<<<128, 256, 0, stream>>>(part, gr, gi, cb, idxb);
    zero_vq<<<1, 1, 0, stream>>>(out, vq_off);
    gather_epi<<<8192, 256, 0, stream>>>(idxb, gr, gi, cb, sw, sb, out,
                                         sal_off, vq_off);
}

// Round 10
// 1270.071 us; speedup vs baseline: 1.2518x; 1.2509x over previous
//
#include <hip/hip_runtime.h>
#include <stdint.h>

// Problem constants
#define MROWS 32768      // B*S = 8*4096
#define KD    256        // 2*DIM
#define VOCABN 8192

typedef _Float16 half8  __attribute__((ext_vector_type(8)));
typedef _Float16 half4v __attribute__((ext_vector_type(4)));
typedef float  floatx4  __attribute__((ext_vector_type(4)));

#define LDA 528    // A LDS row stride: 512 B data + 16 B pad (2-way alias = free)
#define LDKB 144   // B LDS row stride: 128 B data + 16 B pad (R4-proven)

// scratch layout (byte offsets within d_ws; ws_size >= WS_NEED verified R3/R4)
#define A_OFF     0u          // f16 z  [32768][256]  = 16,777,216 B
#define B_OFF     16777216u   // f16 cb [8192][256]   =  4,194,304 B
#define CN_OFF    20971520u   // f32 0.5*||c||^2 [8192] = 32,768 B
#define PART_OFF  21004288u   // float4 top2 [32768][8] = 4,194,304 B
#define IDX_OFF   25198592u   // int idx [32768] = 131,072 B
#define WS_NEED   25329664u

// ---- top-2 (max sigma) with smaller-index tie-break ----
struct Top2 { float s1; int i1; float s2; int i2; };

__device__ __forceinline__ bool better(float sa, int ia, float sb, int ib) {
    return (sa > sb) || (sa == sb && ia < ib);
}
__device__ __forceinline__ Top2 merge2(const Top2& a, const Top2& b) {
    Top2 r;
    if (better(b.s1, b.i1, a.s1, a.i1)) {
        r.s1 = b.s1; r.i1 = b.i1;
        if (better(a.s1, a.i1, b.s2, b.i2)) { r.s2 = a.s1; r.i2 = a.i1; }
        else                                { r.s2 = b.s2; r.i2 = b.i2; }
    } else {
        r.s1 = a.s1; r.i1 = a.i1;
        if (better(b.s1, b.i1, a.s2, a.i2)) { r.s2 = b.s1; r.i2 = b.i1; }
        else                                { r.s2 = a.s2; r.i2 = a.i2; }
    }
    return r;
}

// ---- 1. z = concat(real,imag) as f16 [32768][256] ----
__global__ __launch_bounds__(256) void prep_z(const float* __restrict__ gr,
                                              const float* __restrict__ gi,
                                              _Float16* __restrict__ A) {
    int t = blockIdx.x * 256 + threadIdx.x;     // 4 elements/thread
    int base = t * 4;
    int m = base >> 8;
    int k = base & 255;
    float4 v;
    if (k < 128) v = *(const float4*)(gr + (size_t)m * 128 + k);
    else         v = *(const float4*)(gi + (size_t)m * 128 + (k - 128));
    half4v h;
    h[0] = (_Float16)v.x; h[1] = (_Float16)v.y;
    h[2] = (_Float16)v.z; h[3] = (_Float16)v.w;
    *(half4v*)(A + base) = h;
}

// ---- 2. codebook f16 [8192][256] + 0.5*||c||^2 fp32 ----
__global__ __launch_bounds__(64) void prep_c(const float* __restrict__ cb,
                                             _Float16* __restrict__ B,
                                             float* __restrict__ cnorm) {
    int v = blockIdx.x;
    int lane = threadIdx.x;                    // 0..63, 4 floats each
    float4 c = ((const float4*)(cb + (size_t)v * 256))[lane];
    half4v h;
    h[0] = (_Float16)c.x; h[1] = (_Float16)c.y;
    h[2] = (_Float16)c.z; h[3] = (_Float16)c.w;
    ((half4v*)(B + (size_t)v * 256))[lane] = h;
    float s = c.x * c.x + c.y * c.y + c.z * c.z + c.w * c.w;
    #pragma unroll
    for (int m = 32; m; m >>= 1) s += __shfl_xor(s, m);
    if (lane == 0) cnorm[v] = 0.5f * s;
}

// ---- 3. f16 GEMM + per-row top-2 argmax(sigma) ----
// grid: 512 blocks (BM=64, all co-resident at 2/CU). A-tile staged ONCE into
// its own LDS region; g-loop streams all 64 N-tiles, staging ONLY B (16 KB/
// stage, R4's staging code verbatim). All blocks march the same 4 MB codebook
// -> B L2-resident. Epilogue is R4's proven LDS datapath (topbuf + rowtop),
// flushed to part[] every 8 g (slot=g>>3) = R4's candidate granularity.
// LDS: 33,792(A) + 18,432(B) + 2,048(topbuf) + 1,024(rowtop) = 55,296 B.
__global__ __launch_bounds__(256) void gemm_argmin(const _Float16* __restrict__ A,
                                                   const _Float16* __restrict__ B,
                                                   const float* __restrict__ cnorm,
                                                   float4* __restrict__ part) {
    __shared__ __align__(16) char   Asm[64 * LDA];     // 33,792 B
    __shared__ __align__(16) char   Bs[128 * LDKB];    // 18,432 B
    __shared__ __align__(16) float4 topbuf[128];       // [64 rows][2 col-halves]
    __shared__ __align__(16) float4 rowtop[64];        // per-row running top2

    const int tid = threadIdx.x;
    const int m0 = blockIdx.x * 64;
    const int wave = tid >> 6, lane = tid & 63;
    const int wr = wave >> 1, wc = wave & 1;           // 2x2: 32 rows x 64 cols
    const int lane16 = lane & 15, quad = lane >> 4;

    // one-time A-tile stage: 64 rows x 512 B; 4 threads/row, 128 B each
    {
        int r = tid >> 2, qo = (tid & 3) * 64;         // f16 element offset
        const _Float16* ag = A + (size_t)(m0 + r) * 256 + qo;
        char* al = Asm + r * LDA + qo * 2;
        uint4 tmp[8];
        #pragma unroll
        for (int i = 0; i < 8; ++i) tmp[i] = *(const uint4*)(ag + i * 8);
        #pragma unroll
        for (int i = 0; i < 8; ++i) *(uint4*)(al + i * 16) = tmp[i];
    }

    if (tid < 64)
        rowtop[tid] = make_float4(-3.4e38f, __int_as_float(0x7fffffff),
                                  -3.4e38f, __int_as_float(0x7fffffff));
    // note: A writes + rowtop init are covered by the first stage's barrier

    for (int g = 0; g < 64; ++g) {
        const int n0 = g * 128;

        float hc[4];
        #pragma unroll
        for (int j = 0; j < 4; ++j)
            hc[j] = cnorm[n0 + wc * 64 + j * 16 + lane16];

        floatx4 acc[2][4];
        #pragma unroll
        for (int i = 0; i < 2; ++i)
            #pragma unroll
            for (int j = 0; j < 4; ++j)
                acc[i][j] = (floatx4){0.f, 0.f, 0.f, 0.f};

        for (int s = 0; s < 4; ++s) {
            const int k0 = s * 64;
            // B tile: 128 rows x 64 f16 = 1024 16B chunks; 4/thread (R4 code)
            uint4 bv[4];
            #pragma unroll
            for (int it = 0; it < 4; ++it) {
                int c = it * 256 + tid;        // 0..1023
                int r = c >> 3, ci = c & 7;
                bv[it] = *(const uint4*)(B + (size_t)(n0 + r) * 256 + k0 + ci * 8);
            }
            __syncthreads();   // previous stage's LDS reads complete (covers A stage too)
            #pragma unroll
            for (int it = 0; it < 4; ++it) {
                int c = it * 256 + tid;
                int r = c >> 3, ci = c & 7;
                *(uint4*)(Bs + r * LDKB + ci * 16) = bv[it];
            }
            __syncthreads();
            #pragma unroll
            for (int ks = 0; ks < 2; ++ks) {
                half8 af[2], bf[4];
                #pragma unroll
                for (int i = 0; i < 2; ++i)
                    af[i] = *(const half8*)(Asm +
                            (wr * 32 + i * 16 + lane16) * LDA
                            + s * 128 + ks * 64 + quad * 16);
                #pragma unroll
                for (int j = 0; j < 4; ++j)
                    bf[j] = *(const half8*)(Bs +
                            (wc * 64 + j * 16 + lane16) * LDKB + ks * 64 + quad * 16);
                #pragma unroll
                for (int i = 0; i < 2; ++i)
                    #pragma unroll
                    for (int j = 0; j < 4; ++j)
                        acc[i][j] = __builtin_amdgcn_mfma_f32_16x16x32_f16(
                            af[i], bf[j], acc[i][j], 0, 0, 0);
            }
        }
        __syncthreads();

        // epilogue (R4 datapath); C/D layout: col=lane&15, row=quad*4+reg [m89]
        #pragma unroll
        for (int i = 0; i < 2; ++i) {
            #pragma unroll
            for (int r = 0; r < 4; ++r) {
                Top2 t; t.s1 = -3.4e38f; t.i1 = 0x7fffffff;
                        t.s2 = -3.4e38f; t.i2 = 0x7fffffff;
                #pragma unroll
                for (int j = 0; j < 4; ++j) {
                    float sv = acc[i][j][r] - hc[j];
                    int col = n0 + wc * 64 + j * 16 + lane16;
                    if (better(sv, col, t.s1, t.i1)) {
                        t.s2 = t.s1; t.i2 = t.i1; t.s1 = sv; t.i1 = col;
                    } else if (better(sv, col, t.s2, t.i2)) {
                        t.s2 = sv; t.i2 = col;
                    }
                }
                #pragma unroll
                for (int m = 1; m < 16; m <<= 1) {
                    Top2 o;
                    o.s1 = __shfl_xor(t.s1, m); o.i1 = __shfl_xor(t.i1, m);
                    o.s2 = __shfl_xor(t.s2, m); o.i2 = __shfl_xor(t.i2, m);
                    t = merge2(t, o);
                }
                if (lane16 == 0) {
                    int rl = wr * 32 + i * 16 + quad * 4 + r;   // 0..63
                    topbuf[rl * 2 + wc] =
                        make_float4(t.s1, __int_as_float(t.i1),
                                    t.s2, __int_as_float(t.i2));
                }
            }
        }
        __syncthreads();
        if (tid < 64) {
            float4 e0 = topbuf[tid * 2 + 0], e1 = topbuf[tid * 2 + 1], rv = rowtop[tid];
            Top2 a{e0.x, __float_as_int(e0.y), e0.z, __float_as_int(e0.w)};
            Top2 b{e1.x, __float_as_int(e1.y), e1.z, __float_as_int(e1.w)};
            Top2 p{rv.x, __float_as_int(rv.y), rv.z, __float_as_int(rv.w)};
            Top2 t = merge2(merge2(a, b), p);
            if ((g & 7) == 7) {
                // flush this 1024-col super-group's top2 -> part, reinit
                part[(size_t)(m0 + tid) * 8 + (g >> 3)] =
                    make_float4(t.s1, __int_as_float(t.i1),
                                t.s2, __int_as_float(t.i2));
                rowtop[tid] = make_float4(-3.4e38f, __int_as_float(0x7fffffff),
                                          -3.4e38f, __int_as_float(0x7fffffff));
            } else {
                rowtop[tid] = make_float4(t.s1, __int_as_float(t.i1),
                                          t.s2, __int_as_float(t.i2));
            }
        }
        __syncthreads();
    }
}

// ---- 4. resolve: merge 8 partials/row, fp64-refine near-ties (R4-proven) ----
__global__ __launch_bounds__(256) void resolve(const float4* __restrict__ part,
                                               const float* __restrict__ gr,
                                               const float* __restrict__ gi,
                                               const float* __restrict__ cb,
                                               int* __restrict__ idx) {
    const int row = blockIdx.x * 256 + threadIdx.x;   // grid 128
    float4 e[8];
    #pragma unroll
    for (int j = 0; j < 8; ++j) e[j] = part[(size_t)row * 8 + j];
    Top2 t{-3.4e38f, 0x7fffffff, -3.4e38f, 0x7fffffff};
    #pragma unroll
    for (int j = 0; j < 8; ++j) {
        Top2 o{e[j].x, __float_as_int(e[j].y), e[j].z, __float_as_int(e[j].w)};
        t = merge2(t, o);
    }
    int best = t.i1;
    const float MARGIN = 0.12f;   // ~7.7 sigma of f16-screen score-diff noise
    if (t.s1 - t.s2 < MARGIN) {
        double bd = 1e300; int bi = 0x7fffffff;
        float cut = t.s1 - MARGIN;
        const float* zr = gr + (size_t)row * 128;
        const float* zi = gi + (size_t)row * 128;
        #pragma unroll
        for (int j = 0; j < 8; ++j) {
            #pragma unroll
            for (int c = 0; c < 2; ++c) {
                float sv = c ? e[j].z : e[j].x;
                int   ci = __float_as_int(c ? e[j].w : e[j].y);
                if (sv >= cut && (unsigned)ci < 8192u) {   // clamp: no wild reads
                    const float* crow = cb + (size_t)ci * 256;
                    double d = 0.0;
                    for (int k = 0; k < 128; ++k) {
                        double a = (double)zr[k] - (double)crow[k];
                        double b = (double)zi[k] - (double)crow[128 + k];
                        d += a * a + b * b;
                    }
                    if (d < bd || (d == bd && ci < bi)) { bd = d; bi = ci; }
                }
            }
        }
        if ((unsigned)bi < 8192u) best = bi;
    }
    idx[row] = ((unsigned)best < 8192u) ? best : 0;
}

// ---- 5a. zero the vq accumulator ----
__global__ void zero_vq(float* __restrict__ out, size_t vq_off) {
    out[vq_off] = 0.f;
}

// ---- 5b. gather + proposal(REAL part only) + salience + vq (one wave/row) ----
__global__ __launch_bounds__(256) void gather_epi(const int* __restrict__ idx,
                                                  const float* __restrict__ gr,
                                                  const float* __restrict__ gi,
                                                  const float* __restrict__ cb,
                                                  const float* __restrict__ salw,
                                                  const float* __restrict__ salb,
                                                  float* __restrict__ out,
                                                  size_t sal_off, size_t vq_off) {
    const int wave = threadIdx.x >> 6, lane = threadIdx.x & 63;
    const int row = blockIdx.x * 4 + wave;
    int id = idx[row];
    if ((unsigned)id >= 8192u) id = 0;   // clamp: no wild reads

    float4 c4 = ((const float4*)(cb + (size_t)id * 256))[lane];
    float4 z4 = (lane < 32) ? ((const float4*)(gr + (size_t)row * 128))[lane]
                            : ((const float4*)(gi + (size_t)row * 128))[lane - 32];

    float dx = c4.x - z4.x, dy = c4.y - z4.y, dz = c4.z - z4.z, dw = c4.w - z4.w;
    float vq = dx * dx + dy * dy + dz * dz + dw * dw;
    float4 w4 = ((const float4*)salw)[lane];
    float sal = c4.x * w4.x + c4.y * w4.y + c4.z * w4.z + c4.w * w4.w;
    #pragma unroll
    for (int m = 1; m < 64; m <<= 1) {
        vq  += __shfl_xor(vq, m);
        sal += __shfl_xor(sal, m);
    }

    // proposal: real part only — lanes 0..31 hold c[0..128) as float4s
    if (lane < 32 && (size_t)(row + 1) * 128 <= sal_off) {
        float4* op = (float4*)(out + (size_t)row * 128);
        op[lane] = c4;
    }
    if (lane == 0 && sal_off + row < vq_off)
        out[sal_off + row] = sal + salb[0];

    __shared__ float vqs[4];
    if (lane == 0) vqs[wave] = vq;
    __syncthreads();
    if (threadIdx.x == 0) {
        float p = (vqs[0] + vqs[1] + vqs[2] + vqs[3]) * (1.25f / 8388608.f);
        atomicAdd(out + vq_off, p);
    }
}

extern "C" void kernel_launch(void* const* d_in, const int* in_sizes, int n_in,
                              void* d_out, int out_size, void* d_ws, size_t ws_size,
                              hipStream_t stream) {
    const float* gr = (const float*)d_in[0];   // gw_real  [8,4096,128]
    const float* gi = (const float*)d_in[1];   // gw_imag  [8,4096,128]
    const float* cb = (const float*)d_in[2];   // codebook [8192,256]
    const float* sw = (const float*)d_in[3];   // sal_w    [1,256]
    const float* sb = (const float*)d_in[4];   // sal_b    [1]
    float* out = (float*)d_out;

    // Output offsets (out_size = 4,227,073 floats:
    // proposal-real 4,194,304 | salience 32,768 | vq_loss 1).
    size_t vq_off  = (size_t)out_size - 1;
    size_t sal_off = (size_t)out_size - 1 - 32768;

    char* base = (char*)d_ws;
    int*  idxb = (int*)(base + IDX_OFF);
    _Float16* A    = (_Float16*)(base + A_OFF);
    _Float16* Bq   = (_Float16*)(base + B_OFF);
    float*    cn   = (float*)   (base + CN_OFF);
    float4*   part = (float4*)  (base + PART_OFF);

    prep_z<<<8192, 256, 0, stream>>>(gr, gi, A);
    prep_c<<<8192, 64, 0, stream>>>(cb, Bq, cn);
    gemm_argmin<<<512, 256, 0, stream>>>(A, Bq, cn, part);
    resolve<<<128, 256, 0, stream>>>(part, gr, gi, cb, idxb);
    zero_vq<<<1, 1, 0, stream>>>(out, vq_off);
    gather_epi<<<8192, 256, 0, stream>>>(idxb, gr, gi, cb, sw, sb, out,
                                         sal_off, vq_off);
}